// Round 1
// baseline (1194.634 us; speedup 1.0000x reference)
//
#include <hip/hip_runtime.h>
#include <hip/hip_bf16.h>

// ---------- constants ----------
#define S_ 1024
#define H_ 2048
#define NH_ 16
#define KVH_ 4
#define HD_ 128
#define IM_ 1408
#define ISH_ 5632
#define E_ 8

typedef __bf16 bf16x8 __attribute__((ext_vector_type(8)));
typedef float f32x4 __attribute__((ext_vector_type(4)));

__device__ __forceinline__ short f2bf(float f) {
  unsigned u = __float_as_uint(f);
  u = u + 0x7FFFu + ((u >> 16) & 1u);   // RTNE
  return (short)(u >> 16);
}

__device__ __forceinline__ f32x4 mfma16(bf16x8 a, bf16x8 b, f32x4 c) {
  return __builtin_amdgcn_mfma_f32_16x16x32_bf16(a, b, c, 0, 0, 0);
}

template<bool MAXOP>
__device__ __forceinline__ float block_reduce(float v, float* sbuf) {
  #pragma unroll
  for (int o = 32; o >= 1; o >>= 1) {
    float t = __shfl_down(v, o);
    v = MAXOP ? fmaxf(v, t) : (v + t);
  }
  int lane = threadIdx.x & 63, w = threadIdx.x >> 6;
  if (lane == 0) sbuf[w] = v;
  __syncthreads();
  float r = sbuf[0];
  #pragma unroll
  for (int i = 1; i < 4; i++) r = MAXOP ? fmaxf(r, sbuf[i]) : (r + sbuf[i]);
  __syncthreads();
  return r;
}

// ---------- generic GEMM ----------
// BMODE 0: B is fp32 [K,N] (weights), converted+transposed during staging.
// BMODE 1: B is bf16 [N,K] (K-contiguous, e.g. K^T / V^T).
// EPI 0: C fp32 = alpha*acc (+bias)        (dense)
// EPI 1: C fp32 = acc + resid              (dense)
// EPI 2: C bf16 = acc                      (dense)
// EPI 3: expert mode, A row = list[off+m], C fp32 row off+m   (gate/up)
// EPI 4: expert mode, A row = off+m, atomicAdd(C[list[off+m]], scale[off+m]*acc)
// EPI 5: dense, atomicAdd(C[m], scale[m]*acc)                 (shared down)
struct GemmP {
  const short* A; long long strideA; int adiv; int lda;
  const void* B; long long strideB; int bdiv; int ldb;
  const float* bias;
  void* C; long long strideC; int cdiv; int ldc;
  const float* resid;
  const int* e_off; const int* e_cnt;
  const int* list; const float* scale;
  float alpha;
  int M, N, K;
  int cskip, ckb;
};

template<int BMODE, int EPI>
__global__ __launch_bounds__(256) void gemm_core(GemmP p) {
  constexpr int BM = 128, BN = 128, BK = 32, BKP = 40;
  __shared__ __align__(16) short As[BM * BKP];
  __shared__ __align__(16) short Bs[BN * BKP];
  const int m0 = blockIdx.y * BM;
  const int n0 = blockIdx.x * BN;
  const int z = blockIdx.z;
  int off = 0, cnt = p.M;
  if constexpr (EPI == 3 || EPI == 4) {
    off = p.e_off[z]; cnt = p.e_cnt[z];
    if (m0 >= cnt) return;
  }
  if (p.cskip && n0 >= m0 + BM) return;
  int kend = p.K;
  if (p.ckb) { kend = m0 + BM; if (kend > p.K) kend = p.K; }

  const short* Ab = p.A + (long long)(z / p.adiv) * p.strideA;
  const float* Wf = nullptr; const short* Bt = nullptr;
  if constexpr (BMODE == 0) Wf = (const float*)p.B + (long long)(z / p.bdiv) * p.strideB;
  else                      Bt = (const short*)p.B + (long long)(z / p.bdiv) * p.strideB;

  const int tid = threadIdx.x;
  const int lane = tid & 63, wid = tid >> 6;
  const int wr = wid >> 1, wc = wid & 1;
  const int kg = lane >> 4, li = lane & 15;

  f32x4 acc[4][4];
  #pragma unroll
  for (int i = 0; i < 4; i++)
    #pragma unroll
    for (int j = 0; j < 4; j++) acc[i][j] = (f32x4){0.f, 0.f, 0.f, 0.f};

  for (int k0 = 0; k0 < kend; k0 += BK) {
    __syncthreads();
    // ---- stage A: BM x BK bf16
    #pragma unroll
    for (int c = 0; c < 2; c++) {
      int chunk = tid + c * 256;            // 0..511
      int row = chunk >> 2, cc = (chunk & 3) << 3;
      int gr;
      if constexpr (EPI == 3) { int rr = m0 + row; if (rr >= cnt) rr = cnt - 1; gr = p.list[off + rr]; }
      else if constexpr (EPI == 4) { int rr = m0 + row; if (rr >= cnt) rr = cnt - 1; gr = off + rr; }
      else gr = m0 + row;
      const int4* src = (const int4*)(Ab + (long long)gr * p.lda + k0 + cc);
      *(int4*)&As[row * BKP + cc] = *src;
    }
    // ---- stage B
    if constexpr (BMODE == 1) {
      #pragma unroll
      for (int c = 0; c < 2; c++) {
        int chunk = tid + c * 256;
        int row = chunk >> 2, cc = (chunk & 3) << 3;
        const int4* src = (const int4*)(Bt + (long long)(n0 + row) * p.ldb + k0 + cc);
        *(int4*)&Bs[row * BKP + cc] = *src;
      }
    } else {
      int nl = tid & 127, kh = tid >> 7;
      const float* Wp = Wf + (long long)(k0 + kh * 16) * p.ldb + n0 + nl;
      #pragma unroll
      for (int hh = 0; hh < 2; hh++) {
        union { short s[8]; int4 v; } tmp;
        #pragma unroll
        for (int kk = 0; kk < 8; kk++)
          tmp.s[kk] = f2bf(Wp[(long long)(hh * 8 + kk) * p.ldb]);
        *(int4*)&Bs[nl * BKP + kh * 16 + hh * 8] = tmp.v;
      }
    }
    __syncthreads();
    bf16x8 av[4], bv[4];
    #pragma unroll
    for (int mi = 0; mi < 4; mi++)
      av[mi] = *(const bf16x8*)&As[(wr * 64 + mi * 16 + li) * BKP + kg * 8];
    #pragma unroll
    for (int nj = 0; nj < 4; nj++)
      bv[nj] = *(const bf16x8*)&Bs[(wc * 64 + nj * 16 + li) * BKP + kg * 8];
    #pragma unroll
    for (int mi = 0; mi < 4; mi++)
      #pragma unroll
      for (int nj = 0; nj < 4; nj++)
        acc[mi][nj] = mfma16(av[mi], bv[nj], acc[mi][nj]);
  }

  long long zc = (long long)(z / p.cdiv) * p.strideC;
  #pragma unroll
  for (int mi = 0; mi < 4; mi++) {
    #pragma unroll
    for (int nj = 0; nj < 4; nj++) {
      #pragma unroll
      for (int r = 0; r < 4; r++) {
        int ml = wr * 64 + mi * 16 + kg * 4 + r;
        int nl2 = wc * 64 + nj * 16 + li;
        int mg = m0 + ml, ng = n0 + nl2;
        float v = acc[mi][nj][r] * p.alpha;
        if constexpr (EPI == 0) {
          float* C = (float*)p.C + zc;
          if (p.bias) v += p.bias[ng];
          C[(long long)mg * p.ldc + ng] = v;
        } else if constexpr (EPI == 1) {
          float* C = (float*)p.C + zc;
          C[(long long)mg * p.ldc + ng] = v + p.resid[(long long)mg * p.ldc + ng];
        } else if constexpr (EPI == 2) {
          short* C = (short*)p.C + zc;
          C[(long long)mg * p.ldc + ng] = f2bf(v);
        } else if constexpr (EPI == 3) {
          if (mg < cnt) {
            float* C = (float*)p.C;
            C[(long long)(off + mg) * p.ldc + ng] = v;
          }
        } else if constexpr (EPI == 4) {
          if (mg < cnt) {
            float* C = (float*)p.C;
            int tok = p.list[off + mg];
            atomicAdd(&C[(long long)tok * p.ldc + ng], p.scale[off + mg] * v);
          }
        } else if constexpr (EPI == 5) {
          float* C = (float*)p.C;
          atomicAdd(&C[(long long)mg * p.ldc + ng], p.scale[mg] * v);
        }
      }
    }
  }
}

// ---------- aux kernels ----------
__global__ __launch_bounds__(256) void rope_table_k(const int* pos_ids, float* ct, float* st) {
  int i = blockIdx.x * 256 + threadIdx.x;          // 1024*64
  int p = i >> 6, f = i & 63;
  float pos = (float)pos_ids[p];
  float inv = powf(1.0e6f, -(float)f * (1.f / 64.f));
  float a = pos * inv;
  ct[i] = cosf(a); st[i] = sinf(a);
}

__global__ __launch_bounds__(256) void rmsnorm_k(const float* x, const float* w, short* o,
                                                 float* copy_out, float* rs_out) {
  __shared__ float sbuf[4];
  int t = blockIdx.x;
  const float* xr = x + (long long)t * H_;
  float ss = 0.f;
  for (int i = threadIdx.x; i < H_ / 4; i += 256) {
    float4 v = ((const float4*)xr)[i];
    ss += v.x * v.x + v.y * v.y + v.z * v.z + v.w * v.w;
  }
  ss = block_reduce<false>(ss, sbuf);
  float rs = rsqrtf(ss * (1.f / (float)H_) + 1e-6f);
  for (int i = threadIdx.x; i < H_; i += 256) {
    float xv = xr[i];
    o[(long long)t * H_ + i] = f2bf(xv * rs * w[i]);
    if (copy_out) copy_out[(long long)t * H_ + i] = xv;
  }
  if (rs_out && threadIdx.x == 0) rs_out[t] = rs;
}

__global__ __launch_bounds__(256) void rope_apply_k(const float* x, short* o, const float* ct,
                                                    const float* st, int nh, int total) {
  int i = blockIdx.x * 256 + threadIdx.x;
  if (i >= total) return;
  int d = i & 127;
  int p = i / (nh * 128);
  int f = d & 63;
  float c = ct[p * 64 + f], s = st[p * 64 + f];
  float xv = x[i];
  float other = (d < 64) ? -x[i + 64] : x[i - 64];
  o[i] = f2bf(xv * c + other * s);
}

__global__ __launch_bounds__(256) void vtrans_k(const float* vf, short* vt) {
  int i = blockIdx.x * 256 + threadIdx.x;          // 4*128*1024
  int kvh = i >> 17, rem = i & 131071;
  int d = rem >> 10, s_ = rem & 1023;
  vt[i] = f2bf(vf[(long long)s_ * (KVH_ * HD_) + kvh * HD_ + d]);
}

__global__ __launch_bounds__(256) void softmax_k(const float* sc, short* P) {
  __shared__ float sbuf[4];
  long long row = blockIdx.x;                      // h*1024+q
  int q = (int)(row & (S_ - 1));
  const float* sr = sc + row * S_;
  short* pr = P + row * S_;
  int L = q + 1;
  float mx = -3.4e38f;
  for (int i = threadIdx.x; i < L; i += 256) mx = fmaxf(mx, sr[i]);
  mx = block_reduce<true>(mx, sbuf);
  float s = 0.f;
  for (int i = threadIdx.x; i < L; i += 256) s += __expf(sr[i] - mx);
  s = block_reduce<false>(s, sbuf);
  float inv = 1.f / s;
  for (int i = threadIdx.x; i < S_; i += 256) {
    float pv = (i < L) ? __expf(sr[i] - mx) * inv : 0.f;
    pr[i] = f2bf(pv);
  }
}

__global__ void router_k(const float* h2, const float* rs, const float* w2,
                         const float* rw, const float* sgw,
                         int* top_i, float* top_w, float* sg_sig, int* counts) {
  int t = blockIdx.x;
  int l = threadIdx.x;   // 64 threads
  float le[8] = {0, 0, 0, 0, 0, 0, 0, 0};
  float ls = 0.f;
  float r = rs[t];
  for (int k = l; k < H_; k += 64) {
    float xv = h2[(long long)t * H_ + k] * r * w2[k];
    ls += xv * sgw[k];
    const float* rk = rw + k * E_;
    #pragma unroll
    for (int e = 0; e < E_; e++) le[e] += xv * rk[e];
  }
  #pragma unroll
  for (int o = 32; o >= 1; o >>= 1) {
    ls += __shfl_down(ls, o);
    #pragma unroll
    for (int e = 0; e < E_; e++) le[e] += __shfl_down(le[e], o);
  }
  if (l == 0) {
    float m = le[0];
    for (int e = 1; e < E_; e++) m = fmaxf(m, le[e]);
    float pe[8], s = 0.f;
    for (int e = 0; e < E_; e++) { pe[e] = __expf(le[e] - m); s += pe[e]; }
    float inv = 1.f / s;
    for (int e = 0; e < E_; e++) pe[e] *= inv;
    int i1 = 0;
    for (int e = 1; e < E_; e++) if (pe[e] > pe[i1]) i1 = e;
    int i2 = -1;
    for (int e = 0; e < E_; e++) if (e != i1 && (i2 < 0 || pe[e] > pe[i2])) i2 = e;
    top_i[2 * t] = i1; top_i[2 * t + 1] = i2;
    top_w[2 * t] = pe[i1]; top_w[2 * t + 1] = pe[i2];
    sg_sig[t] = 1.f / (1.f + __expf(-ls));
    atomicAdd(&counts[i1], 1); atomicAdd(&counts[i2], 1);
  }
}

__global__ void scan_k(const int* counts, int* offs) {
  if (threadIdx.x == 0 && blockIdx.x == 0) {
    int s = 0;
    for (int e = 0; e < E_; e++) { offs[e] = s; s += counts[e]; }
  }
}

__global__ __launch_bounds__(256) void fill_k(const int* top_i, const float* top_w, const int* offs,
                                              int* pos, int* list, float* pw) {
  int t = blockIdx.x * 256 + threadIdx.x;
  if (t >= S_) return;
  for (int j = 0; j < 2; j++) {
    int e = top_i[2 * t + j];
    int p_ = atomicAdd(&pos[e], 1);
    int slot = offs[e] + p_;
    list[slot] = t; pw[slot] = top_w[2 * t + j];
  }
}

__global__ __launch_bounds__(256) void silu_mul_k(const float* g, const float* u, short* o, int total) {
  int i = blockIdx.x * 256 + threadIdx.x;
  if (i >= total) return;
  float gv = g[i];
  float sig = 1.f / (1.f + __expf(-gv));
  o[i] = f2bf(gv * sig * u[i]);
}

// ---------- host ----------
static GemmP mkp() {
  GemmP p{};
  p.adiv = 1; p.bdiv = 1; p.cdiv = 1; p.alpha = 1.f;
  return p;
}

extern "C" void kernel_launch(void* const* d_in, const int* in_sizes, int n_in,
                              void* d_out, int out_size, void* d_ws, size_t ws_size,
                              hipStream_t stream) {
  const float* hidden   = (const float*)d_in[0];
  const int*   pos_ids  = (const int*)d_in[1];
  const float* ln1_w    = (const float*)d_in[2];
  const float* ln2_w    = (const float*)d_in[3];
  const float* q_w      = (const float*)d_in[4];
  const float* q_b      = (const float*)d_in[5];
  const float* k_w      = (const float*)d_in[6];
  const float* k_b      = (const float*)d_in[7];
  const float* v_w      = (const float*)d_in[8];
  const float* v_b      = (const float*)d_in[9];
  const float* o_w      = (const float*)d_in[10];
  const float* router_w = (const float*)d_in[11];
  const float* e_gate   = (const float*)d_in[12];
  const float* e_up     = (const float*)d_in[13];
  const float* e_down   = (const float*)d_in[14];
  const float* s_gate   = (const float*)d_in[15];
  const float* s_up     = (const float*)d_in[16];
  const float* s_down   = (const float*)d_in[17];
  const float* sg_w     = (const float*)d_in[18];
  float* out = (float*)d_out;

  char* base = (char*)d_ws;
  size_t off_ = 0;
  auto alc = [&](size_t nbytes) -> char* {
    off_ = (off_ + 255) & ~(size_t)255;
    char* p = base + off_;
    off_ += nbytes;
    return p;
  };
  short* x1     = (short*)alc((size_t)S_ * H_ * 2);
  float* qf     = (float*)alc((size_t)S_ * H_ * 4);
  float* kf     = (float*)alc((size_t)S_ * KVH_ * HD_ * 4);
  float* vf     = (float*)alc((size_t)S_ * KVH_ * HD_ * 4);
  float* ct     = (float*)alc((size_t)S_ * 64 * 4);
  float* st     = (float*)alc((size_t)S_ * 64 * 4);
  short* qr     = (short*)alc((size_t)S_ * H_ * 2);
  short* kr     = (short*)alc((size_t)S_ * KVH_ * HD_ * 2);
  short* vt     = (short*)alc((size_t)S_ * KVH_ * HD_ * 2);
  short* attn   = (short*)alc((size_t)S_ * H_ * 2);
  float* h2     = (float*)alc((size_t)S_ * H_ * 4);
  short* x2     = (short*)alc((size_t)S_ * H_ * 2);
  float* rs2    = (float*)alc(S_ * 4);
  int*   top_i  = (int*)alc(2 * S_ * 4);
  float* top_w  = (float*)alc(2 * S_ * 4);
  float* sg_sig = (float*)alc(S_ * 4);
  int*   counts = (int*)alc(64);            // counts[8] + pos[8]
  int*   pos    = counts + 8;
  int*   offs   = (int*)alc(32);
  int*   list   = (int*)alc(2 * S_ * 4);
  float* pw     = (float*)alc(2 * S_ * 4);
  char*  region = alc(100663296);           // 96 MiB: scores+P, later MoE overlay
  float* scores = (float*)region;
  short* P      = (short*)(region + 67108864);
  float* g_moe  = (float*)region;
  float* u_moe  = (float*)(region + 11534336);
  short* gu_moe = (short*)(region + 23068672);
  float* g_sh   = (float*)(region + 28835840);
  float* u_sh   = (float*)(region + 51904512);
  short* gu_sh  = (short*)(region + 74973184);

  // 1) rope tables + rmsnorm1
  rope_table_k<<<256, 256, 0, stream>>>(pos_ids, ct, st);
  rmsnorm_k<<<S_, 256, 0, stream>>>(hidden, ln1_w, x1, nullptr, nullptr);

  // 2) Q/K/V projections
  {
    GemmP p = mkp();
    p.A = x1; p.lda = H_;
    p.B = q_w; p.ldb = H_; p.bias = q_b;
    p.C = qf; p.ldc = H_;
    p.M = S_; p.N = H_; p.K = H_;
    gemm_core<0, 0><<<dim3(16, 8, 1), 256, 0, stream>>>(p);
    p.B = k_w; p.ldb = 512; p.bias = k_b; p.C = kf; p.ldc = 512; p.N = 512;
    gemm_core<0, 0><<<dim3(4, 8, 1), 256, 0, stream>>>(p);
    p.B = v_w; p.bias = v_b; p.C = vf;
    gemm_core<0, 0><<<dim3(4, 8, 1), 256, 0, stream>>>(p);
  }

  // 3) RoPE + V transpose
  rope_apply_k<<<8192, 256, 0, stream>>>(qf, qr, ct, st, NH_, S_ * H_);
  rope_apply_k<<<2048, 256, 0, stream>>>(kf, kr, ct, st, KVH_, S_ * KVH_ * HD_);
  vtrans_k<<<2048, 256, 0, stream>>>(vf, vt);

  // 4) scores = scale * Q K^T (causal tiles only)
  {
    GemmP p = mkp();
    p.A = qr; p.strideA = HD_; p.lda = H_;
    p.B = kr; p.strideB = HD_; p.bdiv = 4; p.ldb = KVH_ * HD_;
    p.C = scores; p.strideC = (long long)S_ * S_; p.ldc = S_;
    p.alpha = 0.08838834764831845f;
    p.M = S_; p.N = S_; p.K = HD_; p.cskip = 1;
    gemm_core<1, 0><<<dim3(8, 8, NH_), 256, 0, stream>>>(p);
  }
  softmax_k<<<NH_ * S_, 256, 0, stream>>>(scores, P);
  // 5) attn = P @ V
  {
    GemmP p = mkp();
    p.A = P; p.strideA = (long long)S_ * S_; p.lda = S_;
    p.B = vt; p.strideB = (long long)HD_ * S_; p.bdiv = 4; p.ldb = S_;
    p.C = attn; p.strideC = HD_; p.ldc = H_;
    p.M = S_; p.N = HD_; p.K = S_; p.ckb = 1;
    gemm_core<1, 2><<<dim3(1, 8, NH_), 256, 0, stream>>>(p);
  }
  // 6) O-proj + residual -> h2
  {
    GemmP p = mkp();
    p.A = attn; p.lda = H_;
    p.B = o_w; p.ldb = H_;
    p.C = h2; p.ldc = H_; p.resid = hidden;
    p.M = S_; p.N = H_; p.K = H_;
    gemm_core<0, 1><<<dim3(16, 8, 1), 256, 0, stream>>>(p);
  }

  // 7) rmsnorm2 (x2 bf16; copy h2 -> d_out as accumulator base; save 1/rms)
  rmsnorm_k<<<S_, 256, 0, stream>>>(h2, ln2_w, x2, out, rs2);

  // 8) router / top-2 / gather lists
  hipMemsetAsync(counts, 0, 64, stream);
  router_k<<<S_, 64, 0, stream>>>(h2, rs2, ln2_w, router_w, sg_w, top_i, top_w, sg_sig, counts);
  scan_k<<<1, 1, 0, stream>>>(counts, offs);
  fill_k<<<4, 256, 0, stream>>>(top_i, top_w, offs, pos, list, pw);

  // 9) expert gate/up (gathered), silu*mul, down (scatter-add to d_out)
  {
    GemmP p = mkp();
    p.A = x2; p.lda = H_;
    p.B = e_gate; p.strideB = (long long)H_ * IM_; p.ldb = IM_;
    p.C = g_moe; p.ldc = IM_;
    p.e_off = offs; p.e_cnt = counts; p.list = list;
    p.M = S_; p.N = IM_; p.K = H_;
    gemm_core<0, 3><<<dim3(11, 8, E_), 256, 0, stream>>>(p);
    p.B = e_up; p.C = u_moe;
    gemm_core<0, 3><<<dim3(11, 8, E_), 256, 0, stream>>>(p);
  }
  silu_mul_k<<<11264, 256, 0, stream>>>(g_moe, u_moe, gu_moe, 2 * S_ * IM_);
  {
    GemmP p = mkp();
    p.A = gu_moe; p.lda = IM_;
    p.B = e_down; p.strideB = (long long)IM_ * H_; p.ldb = H_;
    p.C = out; p.ldc = H_;
    p.e_off = offs; p.e_cnt = counts; p.list = list; p.scale = pw;
    p.M = S_; p.N = H_; p.K = IM_;
    gemm_core<0, 4><<<dim3(16, 8, E_), 256, 0, stream>>>(p);
  }

  // 10) shared expert
  {
    GemmP p = mkp();
    p.A = x2; p.lda = H_;
    p.B = s_gate; p.ldb = ISH_;
    p.C = g_sh; p.ldc = ISH_;
    p.M = S_; p.N = ISH_; p.K = H_;
    gemm_core<0, 0><<<dim3(44, 8, 1), 256, 0, stream>>>(p);
    p.B = s_up; p.C = u_sh;
    gemm_core<0, 0><<<dim3(44, 8, 1), 256, 0, stream>>>(p);
  }
  silu_mul_k<<<22528, 256, 0, stream>>>(g_sh, u_sh, gu_sh, S_ * ISH_);
  {
    GemmP p = mkp();
    p.A = gu_sh; p.lda = ISH_;
    p.B = s_down; p.ldb = H_;
    p.C = out; p.ldc = H_; p.scale = sg_sig;
    p.M = S_; p.N = H_; p.K = ISH_;
    gemm_core<0, 5><<<dim3(16, 8, 1), 256, 0, stream>>>(p);
  }
}

// Round 2
// 1098.615 us; speedup vs baseline: 1.0874x; 1.0874x over previous
//
#include <hip/hip_runtime.h>
#include <hip/hip_bf16.h>

// ---------- constants ----------
#define S_ 1024
#define H_ 2048
#define NH_ 16
#define KVH_ 4
#define HD_ 128
#define IM_ 1408
#define ISH_ 5632
#define E_ 8

typedef __bf16 bf16x8 __attribute__((ext_vector_type(8)));
typedef float f32x4 __attribute__((ext_vector_type(4)));

typedef unsigned int __attribute__((address_space(1))) as1_u32;
typedef unsigned int __attribute__((address_space(3))) as3_u32;

__device__ __forceinline__ void gload16(const void* g, void* l) {
  __builtin_amdgcn_global_load_lds((const as1_u32*)g, (as3_u32*)l, 16, 0, 0);
}

__device__ __forceinline__ short f2bf(float f) {
  unsigned u = __float_as_uint(f);
  u = u + 0x7FFFu + ((u >> 16) & 1u);   // RTNE
  return (short)(u >> 16);
}

__device__ __forceinline__ f32x4 mfma16(bf16x8 a, bf16x8 b, f32x4 c) {
  return __builtin_amdgcn_mfma_f32_16x16x32_bf16(a, b, c, 0, 0, 0);
}

template<bool MAXOP>
__device__ __forceinline__ float block_reduce(float v, float* sbuf) {
  #pragma unroll
  for (int o = 32; o >= 1; o >>= 1) {
    float t = __shfl_down(v, o);
    v = MAXOP ? fmaxf(v, t) : (v + t);
  }
  int lane = threadIdx.x & 63, w = threadIdx.x >> 6;
  if (lane == 0) sbuf[w] = v;
  __syncthreads();
  float r = sbuf[0];
  #pragma unroll
  for (int i = 1; i < 4; i++) r = MAXOP ? fmaxf(r, sbuf[i]) : (r + sbuf[i]);
  __syncthreads();
  return r;
}

// ---------- transpose+convert: src fp32 [z][R][C] -> dst bf16 [z][C][R] ----------
__global__ __launch_bounds__(256) void transpose_k(const float* src, short* dst, int R, int C) {
  __shared__ short tile[64][72];   // 72*2=144B row stride: 16B aligned, padded
  const size_t zoff = (size_t)blockIdx.z * R * C;
  src += zoff; dst += zoff;
  const int r0 = blockIdx.y * 64, c0 = blockIdx.x * 64;
  const int t = threadIdx.x;
  const int tr = t >> 4, tc4 = (t & 15) * 4;
  #pragma unroll
  for (int i = 0; i < 4; i++) {
    int r = tr + i * 16;
    float4 v = *(const float4*)&src[(size_t)(r0 + r) * C + c0 + tc4];
    tile[tc4 + 0][r] = f2bf(v.x);
    tile[tc4 + 1][r] = f2bf(v.y);
    tile[tc4 + 2][r] = f2bf(v.z);
    tile[tc4 + 3][r] = f2bf(v.w);
  }
  __syncthreads();
  const int row = t >> 2, kc = (t & 3) * 16;
  #pragma unroll
  for (int j = 0; j < 2; j++) {
    int kcol = kc + j * 8;
    *(int4*)&dst[(size_t)(c0 + row) * R + r0 + kcol] = *(const int4*)&tile[row][kcol];
  }
}

// ---------- GEMM: A bf16 [M,K], B bf16 [N,K] (both K-contig), m97 structure ----------
// EPI 0: C fp32 = alpha*acc (+bias)
// EPI 1: C fp32 = acc + resid
// EPI 2: C bf16 = acc
// EPI 3: expert: A row = list[off+m], C fp32 row off+m
// EPI 4: expert: A row = off+m, atomicAdd(C[list[off+m]], scale[off+m]*acc)
// EPI 5: dense: atomicAdd(C[m], scale[m]*acc)
struct GemmP {
  const short* A; long long strideA; int adiv; int lda;
  const short* B; long long strideB; int bdiv; int ldb;
  const float* bias;
  void* C; long long strideC; int cdiv; int ldc;
  const float* resid;
  const int* e_off; const int* e_cnt;
  const int* list; const float* scale;
  float alpha;
  int M, N, K;
  int cskip, ckb;
};

template<int EPI>
__global__ __launch_bounds__(256) void gemm_bt(GemmP p) {
  constexpr int BM = 128, BN = 128, BK = 32;
  __shared__ __align__(16) short As[BM * BK];
  __shared__ __align__(16) short Bs[BN * BK];
  const int m0 = blockIdx.y * BM;
  const int n0 = blockIdx.x * BN;
  const int z = blockIdx.z;
  int off = 0, cnt = p.M;
  if constexpr (EPI == 3 || EPI == 4) {
    off = p.e_off[z]; cnt = p.e_cnt[z];
    if (m0 >= cnt) return;
  }
  if (p.cskip && n0 >= m0 + BM) return;
  const int kend = p.ckb ? min(m0 + BM, p.K) : p.K;

  const short* Ab = p.A + (long long)(z / p.adiv) * p.strideA;
  const short* Bb = p.B + (long long)(z / p.bdiv) * p.strideB;

  const int tid = threadIdx.x;
  const int lane = tid & 63, wid = tid >> 6;
  const int wr = wid >> 1, wc = wid & 1;
  const int kg = lane >> 4, li = lane & 15;

  // per-thread staging sources (fixed across K-loop)
  const int srow = tid >> 2, scol = (tid & 3) * 8;
  const short* aSrc[2];
  const short* bSrc[2];
  #pragma unroll
  for (int c = 0; c < 2; c++) {
    int ra = srow + c * 64;
    int gr;
    if constexpr (EPI == 3)      { int rr = m0 + ra; if (rr >= cnt) rr = cnt - 1; gr = p.list[off + rr]; }
    else if constexpr (EPI == 4) { int rr = m0 + ra; if (rr >= cnt) rr = cnt - 1; gr = off + rr; }
    else                         gr = m0 + ra;
    aSrc[c] = Ab + (long long)gr * p.lda + scol;
    bSrc[c] = Bb + (long long)(n0 + ra) * p.ldb + scol;
  }

  f32x4 acc[4][4];
  #pragma unroll
  for (int i = 0; i < 4; i++)
    #pragma unroll
    for (int j = 0; j < 4; j++) acc[i][j] = (f32x4){0.f, 0.f, 0.f, 0.f};

  for (int k0 = 0; k0 < kend; k0 += BK) {
    __syncthreads();
    #pragma unroll
    for (int c = 0; c < 2; c++) {
      gload16(aSrc[c] + k0, &As[tid * 8 + c * 2048]);
      gload16(bSrc[c] + k0, &Bs[tid * 8 + c * 2048]);
    }
    __syncthreads();
    bf16x8 av[4], bv[4];
    #pragma unroll
    for (int mi = 0; mi < 4; mi++)
      av[mi] = *(const bf16x8*)&As[(wr * 64 + mi * 16 + li) * BK + kg * 8];
    #pragma unroll
    for (int nj = 0; nj < 4; nj++)
      bv[nj] = *(const bf16x8*)&Bs[(wc * 64 + nj * 16 + li) * BK + kg * 8];
    #pragma unroll
    for (int mi = 0; mi < 4; mi++)
      #pragma unroll
      for (int nj = 0; nj < 4; nj++)
        acc[mi][nj] = mfma16(av[mi], bv[nj], acc[mi][nj]);
  }

  const long long zc = (long long)(z / p.cdiv) * p.strideC;
  #pragma unroll
  for (int mi = 0; mi < 4; mi++) {
    #pragma unroll
    for (int nj = 0; nj < 4; nj++) {
      #pragma unroll
      for (int r = 0; r < 4; r++) {
        int ml = wr * 64 + mi * 16 + kg * 4 + r;
        int nl2 = wc * 64 + nj * 16 + li;
        int mg = m0 + ml, ng = n0 + nl2;
        float v = acc[mi][nj][r] * p.alpha;
        if constexpr (EPI == 0) {
          float* C = (float*)p.C + zc;
          if (p.bias) v += p.bias[ng];
          C[(long long)mg * p.ldc + ng] = v;
        } else if constexpr (EPI == 1) {
          float* C = (float*)p.C + zc;
          C[(long long)mg * p.ldc + ng] = v + p.resid[(long long)mg * p.ldc + ng];
        } else if constexpr (EPI == 2) {
          short* C = (short*)p.C + zc;
          C[(long long)mg * p.ldc + ng] = f2bf(v);
        } else if constexpr (EPI == 3) {
          if (mg < cnt) {
            float* C = (float*)p.C;
            C[(long long)(off + mg) * p.ldc + ng] = v;
          }
        } else if constexpr (EPI == 4) {
          if (mg < cnt) {
            float* C = (float*)p.C;
            int tok = p.list[off + mg];
            atomicAdd(&C[(long long)tok * p.ldc + ng], p.scale[off + mg] * v);
          }
        } else if constexpr (EPI == 5) {
          float* C = (float*)p.C;
          atomicAdd(&C[(long long)mg * p.ldc + ng], p.scale[mg] * v);
        }
      }
    }
  }
}

// ---------- aux kernels ----------
__global__ __launch_bounds__(256) void rope_table_k(const int* pos_ids, float* ct, float* st) {
  int i = blockIdx.x * 256 + threadIdx.x;          // 1024*64
  int p = i >> 6, f = i & 63;
  float pos = (float)pos_ids[p];
  float inv = powf(1.0e6f, -(float)f * (1.f / 64.f));
  float a = pos * inv;
  ct[i] = cosf(a); st[i] = sinf(a);
}

__global__ __launch_bounds__(256) void rmsnorm_k(const float* x, const float* w, short* o,
                                                 float* copy_out, float* rs_out) {
  __shared__ float sbuf[4];
  int t = blockIdx.x;
  const float* xr = x + (long long)t * H_;
  float ss = 0.f;
  for (int i = threadIdx.x; i < H_ / 4; i += 256) {
    float4 v = ((const float4*)xr)[i];
    ss += v.x * v.x + v.y * v.y + v.z * v.z + v.w * v.w;
  }
  ss = block_reduce<false>(ss, sbuf);
  float rs = rsqrtf(ss * (1.f / (float)H_) + 1e-6f);
  for (int i = threadIdx.x; i < H_; i += 256) {
    float xv = xr[i];
    o[(long long)t * H_ + i] = f2bf(xv * rs * w[i]);
    if (copy_out) copy_out[(long long)t * H_ + i] = xv;
  }
  if (rs_out && threadIdx.x == 0) rs_out[t] = rs;
}

__global__ __launch_bounds__(256) void rope_apply_k(const float* x, short* o, const float* ct,
                                                    const float* st, int nh, int total) {
  int i = blockIdx.x * 256 + threadIdx.x;
  if (i >= total) return;
  int d = i & 127;
  int p = i / (nh * 128);
  int f = d & 63;
  float c = ct[p * 64 + f], s = st[p * 64 + f];
  float xv = x[i];
  float other = (d < 64) ? -x[i + 64] : x[i - 64];
  o[i] = f2bf(xv * c + other * s);
}

__global__ __launch_bounds__(256) void vtrans_k(const float* vf, short* vt) {
  int i = blockIdx.x * 256 + threadIdx.x;          // 4*128*1024
  int kvh = i >> 17, rem = i & 131071;
  int d = rem >> 10, s_ = rem & 1023;
  vt[i] = f2bf(vf[(long long)s_ * (KVH_ * HD_) + kvh * HD_ + d]);
}

__global__ __launch_bounds__(256) void softmax_k(const float* sc, short* P) {
  __shared__ float sbuf[4];
  long long row = blockIdx.x;                      // h*1024+q
  int q = (int)(row & (S_ - 1));
  const float* sr = sc + row * S_;
  short* pr = P + row * S_;
  int L = q + 1;
  float mx = -3.4e38f;
  for (int i = threadIdx.x; i < L; i += 256) mx = fmaxf(mx, sr[i]);
  mx = block_reduce<true>(mx, sbuf);
  float s = 0.f;
  for (int i = threadIdx.x; i < L; i += 256) s += __expf(sr[i] - mx);
  s = block_reduce<false>(s, sbuf);
  float inv = 1.f / s;
  for (int i = threadIdx.x; i < S_; i += 256) {
    float pv = (i < L) ? __expf(sr[i] - mx) * inv : 0.f;
    pr[i] = f2bf(pv);
  }
}

__global__ void router_k(const float* h2, const float* rs, const float* w2,
                         const float* rw, const float* sgw,
                         int* top_i, float* top_w, float* sg_sig, int* counts) {
  int t = blockIdx.x;
  int l = threadIdx.x;   // 64 threads
  float le[8] = {0, 0, 0, 0, 0, 0, 0, 0};
  float ls = 0.f;
  float r = rs[t];
  for (int k = l; k < H_; k += 64) {
    float xv = h2[(long long)t * H_ + k] * r * w2[k];
    ls += xv * sgw[k];
    const float* rk = rw + k * E_;
    #pragma unroll
    for (int e = 0; e < E_; e++) le[e] += xv * rk[e];
  }
  #pragma unroll
  for (int o = 32; o >= 1; o >>= 1) {
    ls += __shfl_down(ls, o);
    #pragma unroll
    for (int e = 0; e < E_; e++) le[e] += __shfl_down(le[e], o);
  }
  if (l == 0) {
    float m = le[0];
    for (int e = 1; e < E_; e++) m = fmaxf(m, le[e]);
    float pe[8], s = 0.f;
    for (int e = 0; e < E_; e++) { pe[e] = __expf(le[e] - m); s += pe[e]; }
    float inv = 1.f / s;
    for (int e = 0; e < E_; e++) pe[e] *= inv;
    int i1 = 0;
    for (int e = 1; e < E_; e++) if (pe[e] > pe[i1]) i1 = e;
    int i2 = -1;
    for (int e = 0; e < E_; e++) if (e != i1 && (i2 < 0 || pe[e] > pe[i2])) i2 = e;
    top_i[2 * t] = i1; top_i[2 * t + 1] = i2;
    top_w[2 * t] = pe[i1]; top_w[2 * t + 1] = pe[i2];
    sg_sig[t] = 1.f / (1.f + __expf(-ls));
    atomicAdd(&counts[i1], 1); atomicAdd(&counts[i2], 1);
  }
}

__global__ void scan_k(const int* counts, int* offs) {
  if (threadIdx.x == 0 && blockIdx.x == 0) {
    int s = 0;
    for (int e = 0; e < E_; e++) { offs[e] = s; s += counts[e]; }
  }
}

__global__ __launch_bounds__(256) void fill_k(const int* top_i, const float* top_w, const int* offs,
                                              int* pos, int* list, float* pw) {
  int t = blockIdx.x * 256 + threadIdx.x;
  if (t >= S_) return;
  for (int j = 0; j < 2; j++) {
    int e = top_i[2 * t + j];
    int p_ = atomicAdd(&pos[e], 1);
    int slot = offs[e] + p_;
    list[slot] = t; pw[slot] = top_w[2 * t + j];
  }
}

__global__ __launch_bounds__(256) void silu_mul_k(const float* g, const float* u, short* o, int total) {
  int i = blockIdx.x * 256 + threadIdx.x;
  if (i >= total) return;
  float gv = g[i];
  float sig = 1.f / (1.f + __expf(-gv));
  o[i] = f2bf(gv * sig * u[i]);
}

// ---------- host ----------
static GemmP mkp() {
  GemmP p{};
  p.adiv = 1; p.bdiv = 1; p.cdiv = 1; p.alpha = 1.f;
  return p;
}

extern "C" void kernel_launch(void* const* d_in, const int* in_sizes, int n_in,
                              void* d_out, int out_size, void* d_ws, size_t ws_size,
                              hipStream_t stream) {
  const float* hidden   = (const float*)d_in[0];
  const int*   pos_ids  = (const int*)d_in[1];
  const float* ln1_w    = (const float*)d_in[2];
  const float* ln2_w    = (const float*)d_in[3];
  const float* q_w      = (const float*)d_in[4];
  const float* q_b      = (const float*)d_in[5];
  const float* k_w      = (const float*)d_in[6];
  const float* k_b      = (const float*)d_in[7];
  const float* v_w      = (const float*)d_in[8];
  const float* v_b      = (const float*)d_in[9];
  const float* o_w      = (const float*)d_in[10];
  const float* router_w = (const float*)d_in[11];
  const float* e_gate   = (const float*)d_in[12];
  const float* e_up     = (const float*)d_in[13];
  const float* e_down   = (const float*)d_in[14];
  const float* s_gate   = (const float*)d_in[15];
  const float* s_up     = (const float*)d_in[16];
  const float* s_down   = (const float*)d_in[17];
  const float* sg_w     = (const float*)d_in[18];
  float* out = (float*)d_out;

  char* base = (char*)d_ws;
  size_t off_ = 0;
  auto alc = [&](size_t nbytes) -> char* {
    off_ = (off_ + 255) & ~(size_t)255;
    char* p = base + off_;
    off_ += nbytes;
    return p;
  };
  // transposed bf16 weights
  short* qT  = (short*)alc((size_t)H_ * H_ * 2);
  short* kT  = (short*)alc((size_t)512 * H_ * 2);
  short* vT  = (short*)alc((size_t)512 * H_ * 2);
  short* oT  = (short*)alc((size_t)H_ * H_ * 2);
  short* egT = (short*)alc((size_t)E_ * IM_ * H_ * 2);
  short* euT = (short*)alc((size_t)E_ * IM_ * H_ * 2);
  short* edT = (short*)alc((size_t)E_ * H_ * IM_ * 2);
  short* sgT = (short*)alc((size_t)ISH_ * H_ * 2);
  short* suT = (short*)alc((size_t)ISH_ * H_ * 2);
  short* sdT = (short*)alc((size_t)H_ * ISH_ * 2);
  // activations
  short* x1     = (short*)alc((size_t)S_ * H_ * 2);
  float* qf     = (float*)alc((size_t)S_ * H_ * 4);
  float* kf     = (float*)alc((size_t)S_ * KVH_ * HD_ * 4);
  float* vf     = (float*)alc((size_t)S_ * KVH_ * HD_ * 4);
  float* ct     = (float*)alc((size_t)S_ * 64 * 4);
  float* st     = (float*)alc((size_t)S_ * 64 * 4);
  short* qr     = (short*)alc((size_t)S_ * H_ * 2);
  short* kr     = (short*)alc((size_t)S_ * KVH_ * HD_ * 2);
  short* vt     = (short*)alc((size_t)S_ * KVH_ * HD_ * 2);
  short* attn   = (short*)alc((size_t)S_ * H_ * 2);
  float* h2     = (float*)alc((size_t)S_ * H_ * 4);
  short* x2     = (short*)alc((size_t)S_ * H_ * 2);
  float* rs2    = (float*)alc(S_ * 4);
  int*   top_i  = (int*)alc(2 * S_ * 4);
  float* top_w  = (float*)alc(2 * S_ * 4);
  float* sg_sig = (float*)alc(S_ * 4);
  int*   counts = (int*)alc(64);            // counts[8] + pos[8]
  int*   pos    = counts + 8;
  int*   offs   = (int*)alc(32);
  int*   list   = (int*)alc(2 * S_ * 4);
  float* pw     = (float*)alc(2 * S_ * 4);
  char*  region = alc(100663296);           // 96 MiB: scores+P, later MoE overlay
  float* scores = (float*)region;
  short* P      = (short*)(region + 67108864);
  float* g_moe  = (float*)region;
  float* u_moe  = (float*)(region + 11534336);
  short* gu_moe = (short*)(region + 23068672);
  float* g_sh   = (float*)(region + 28835840);
  float* u_sh   = (float*)(region + 51904512);
  short* gu_sh  = (short*)(region + 74973184);

  // 0) weight transpose+convert (fp32 [K,N] -> bf16 [N,K])
  transpose_k<<<dim3(32, 32, 1), 256, 0, stream>>>(q_w, qT, H_, H_);
  transpose_k<<<dim3(8, 32, 1), 256, 0, stream>>>(k_w, kT, H_, 512);
  transpose_k<<<dim3(8, 32, 1), 256, 0, stream>>>(v_w, vT, H_, 512);
  transpose_k<<<dim3(32, 32, 1), 256, 0, stream>>>(o_w, oT, H_, H_);
  transpose_k<<<dim3(22, 32, E_), 256, 0, stream>>>(e_gate, egT, H_, IM_);
  transpose_k<<<dim3(22, 32, E_), 256, 0, stream>>>(e_up, euT, H_, IM_);
  transpose_k<<<dim3(32, 22, E_), 256, 0, stream>>>(e_down, edT, IM_, H_);
  transpose_k<<<dim3(88, 32, 1), 256, 0, stream>>>(s_gate, sgT, H_, ISH_);
  transpose_k<<<dim3(88, 32, 1), 256, 0, stream>>>(s_up, suT, H_, ISH_);
  transpose_k<<<dim3(32, 88, 1), 256, 0, stream>>>(s_down, sdT, ISH_, H_);

  // 1) rope tables + rmsnorm1
  rope_table_k<<<256, 256, 0, stream>>>(pos_ids, ct, st);
  rmsnorm_k<<<S_, 256, 0, stream>>>(hidden, ln1_w, x1, nullptr, nullptr);

  // 2) Q/K/V projections
  {
    GemmP p = mkp();
    p.A = x1; p.lda = H_;
    p.B = qT; p.ldb = H_; p.bias = q_b;
    p.C = qf; p.ldc = H_;
    p.M = S_; p.N = H_; p.K = H_;
    gemm_bt<0><<<dim3(16, 8, 1), 256, 0, stream>>>(p);
    p.B = kT; p.bias = k_b; p.C = kf; p.ldc = 512; p.N = 512;
    gemm_bt<0><<<dim3(4, 8, 1), 256, 0, stream>>>(p);
    p.B = vT; p.bias = v_b; p.C = vf;
    gemm_bt<0><<<dim3(4, 8, 1), 256, 0, stream>>>(p);
  }

  // 3) RoPE + V transpose
  rope_apply_k<<<8192, 256, 0, stream>>>(qf, qr, ct, st, NH_, S_ * H_);
  rope_apply_k<<<2048, 256, 0, stream>>>(kf, kr, ct, st, KVH_, S_ * KVH_ * HD_);
  vtrans_k<<<2048, 256, 0, stream>>>(vf, vt);

  // 4) scores = scale * Q K^T (causal tiles only)
  {
    GemmP p = mkp();
    p.A = qr; p.strideA = HD_; p.lda = H_;
    p.B = kr; p.strideB = HD_; p.bdiv = 4; p.ldb = KVH_ * HD_;
    p.C = scores; p.strideC = (long long)S_ * S_; p.ldc = S_;
    p.alpha = 0.08838834764831845f;
    p.M = S_; p.N = S_; p.K = HD_; p.cskip = 1;
    gemm_bt<0><<<dim3(8, 8, NH_), 256, 0, stream>>>(p);
  }
  softmax_k<<<NH_ * S_, 256, 0, stream>>>(scores, P);
  // 5) attn = P @ V
  {
    GemmP p = mkp();
    p.A = P; p.strideA = (long long)S_ * S_; p.lda = S_;
    p.B = vt; p.strideB = (long long)HD_ * S_; p.bdiv = 4; p.ldb = S_;
    p.C = attn; p.strideC = HD_; p.ldc = H_;
    p.M = S_; p.N = HD_; p.K = S_; p.ckb = 1;
    gemm_bt<2><<<dim3(1, 8, NH_), 256, 0, stream>>>(p);
  }
  // 6) O-proj + residual -> h2
  {
    GemmP p = mkp();
    p.A = attn; p.lda = H_;
    p.B = oT; p.ldb = H_;
    p.C = h2; p.ldc = H_; p.resid = hidden;
    p.M = S_; p.N = H_; p.K = H_;
    gemm_bt<1><<<dim3(16, 8, 1), 256, 0, stream>>>(p);
  }

  // 7) rmsnorm2 (x2 bf16; copy h2 -> d_out as accumulator base; save 1/rms)
  rmsnorm_k<<<S_, 256, 0, stream>>>(h2, ln2_w, x2, out, rs2);

  // 8) router / top-2 / gather lists
  hipMemsetAsync(counts, 0, 64, stream);
  router_k<<<S_, 64, 0, stream>>>(h2, rs2, ln2_w, router_w, sg_w, top_i, top_w, sg_sig, counts);
  scan_k<<<1, 1, 0, stream>>>(counts, offs);
  fill_k<<<4, 256, 0, stream>>>(top_i, top_w, offs, pos, list, pw);

  // 9) expert gate/up (gathered), silu*mul, down (scatter-add to d_out)
  {
    GemmP p = mkp();
    p.A = x2; p.lda = H_;
    p.B = egT; p.strideB = (long long)IM_ * H_; p.ldb = H_;
    p.C = g_moe; p.ldc = IM_;
    p.e_off = offs; p.e_cnt = counts; p.list = list;
    p.M = S_; p.N = IM_; p.K = H_;
    gemm_bt<3><<<dim3(11, 8, E_), 256, 0, stream>>>(p);
    p.B = euT; p.C = u_moe;
    gemm_bt<3><<<dim3(11, 8, E_), 256, 0, stream>>>(p);
  }
  silu_mul_k<<<11264, 256, 0, stream>>>(g_moe, u_moe, gu_moe, 2 * S_ * IM_);
  {
    GemmP p = mkp();
    p.A = gu_moe; p.lda = IM_;
    p.B = edT; p.strideB = (long long)H_ * IM_; p.ldb = IM_;
    p.C = out; p.ldc = H_;
    p.e_off = offs; p.e_cnt = counts; p.list = list; p.scale = pw;
    p.M = S_; p.N = H_; p.K = IM_;
    gemm_bt<4><<<dim3(16, 8, E_), 256, 0, stream>>>(p);
  }

  // 10) shared expert
  {
    GemmP p = mkp();
    p.A = x2; p.lda = H_;
    p.B = sgT; p.ldb = H_;
    p.C = g_sh; p.ldc = ISH_;
    p.M = S_; p.N = ISH_; p.K = H_;
    gemm_bt<0><<<dim3(44, 8, 1), 256, 0, stream>>>(p);
    p.B = suT; p.C = u_sh;
    gemm_bt<0><<<dim3(44, 8, 1), 256, 0, stream>>>(p);
  }
  silu_mul_k<<<22528, 256, 0, stream>>>(g_sh, u_sh, gu_sh, S_ * ISH_);
  {
    GemmP p = mkp();
    p.A = gu_sh; p.lda = ISH_;
    p.B = sdT; p.ldb = ISH_;
    p.C = out; p.ldc = H_; p.scale = sg_sig;
    p.M = S_; p.N = H_; p.K = ISH_;
    gemm_bt<5><<<dim3(16, 8, 1), 256, 0, stream>>>(p);
  }
}

// Round 3
// 706.688 us; speedup vs baseline: 1.6905x; 1.5546x over previous
//
#include <hip/hip_runtime.h>
#include <hip/hip_bf16.h>

// ---------- constants ----------
#define S_ 1024
#define H_ 2048
#define NH_ 16
#define KVH_ 4
#define HD_ 128
#define IM_ 1408
#define ISH_ 5632
#define E_ 8

typedef __bf16 bf16x8 __attribute__((ext_vector_type(8)));
typedef float f32x4 __attribute__((ext_vector_type(4)));

typedef unsigned int __attribute__((address_space(1))) as1_u32;
typedef unsigned int __attribute__((address_space(3))) as3_u32;

__device__ __forceinline__ void gload16(const void* g, void* l) {
  __builtin_amdgcn_global_load_lds((const as1_u32*)g, (as3_u32*)l, 16, 0, 0);
}

__device__ __forceinline__ short f2bf(float f) {
  unsigned u = __float_as_uint(f);
  u = u + 0x7FFFu + ((u >> 16) & 1u);   // RTNE
  return (short)(u >> 16);
}

__device__ __forceinline__ f32x4 mfma16(bf16x8 a, bf16x8 b, f32x4 c) {
  return __builtin_amdgcn_mfma_f32_16x16x32_bf16(a, b, c, 0, 0, 0);
}

template<bool MAXOP>
__device__ __forceinline__ float block_reduce(float v, float* sbuf) {
  #pragma unroll
  for (int o = 32; o >= 1; o >>= 1) {
    float t = __shfl_down(v, o);
    v = MAXOP ? fmaxf(v, t) : (v + t);
  }
  int lane = threadIdx.x & 63, w = threadIdx.x >> 6;
  if (lane == 0) sbuf[w] = v;
  __syncthreads();
  float r = sbuf[0];
  #pragma unroll
  for (int i = 1; i < 4; i++) r = MAXOP ? fmaxf(r, sbuf[i]) : (r + sbuf[i]);
  __syncthreads();
  return r;
}

// ---------- transpose+convert: src fp32 [z][R][C] -> dst bf16 [z][C][R] ----------
__global__ __launch_bounds__(256) void transpose_k(const float* src, short* dst, int R, int C,
                                                   long long srcZ, long long dstZ) {
  __shared__ short tile[64][72];
  src += (long long)blockIdx.z * srcZ;
  dst += (long long)blockIdx.z * dstZ;
  const int r0 = blockIdx.y * 64, c0 = blockIdx.x * 64;
  const int t = threadIdx.x;
  const int tr = t >> 4, tc4 = (t & 15) * 4;
  #pragma unroll
  for (int i = 0; i < 4; i++) {
    int r = tr + i * 16;
    float4 v = *(const float4*)&src[(size_t)(r0 + r) * C + c0 + tc4];
    tile[tc4 + 0][r] = f2bf(v.x);
    tile[tc4 + 1][r] = f2bf(v.y);
    tile[tc4 + 2][r] = f2bf(v.z);
    tile[tc4 + 3][r] = f2bf(v.w);
  }
  __syncthreads();
  const int row = t >> 2, kc = (t & 3) * 16;
  #pragma unroll
  for (int j = 0; j < 2; j++) {
    int kcol = kc + j * 8;
    *(int4*)&dst[(size_t)(c0 + row) * R + r0 + kcol] = *(const int4*)&tile[row][kcol];
  }
}

// ---------- GEMM: A bf16 [M,K], B bf16 [N,K] (K-contig), 2-phase dbuf, split-K ----------
// EPI 0: C fp32 = alpha*acc                          (plain store, ksplit==1 only)
// EPI 1: atomicAdd(C, alpha*acc)                     (split-K dense)
// EPI 3: expert: A row = list[off+m], atomicAdd(C[(off+m)*ldc+n], acc)
// EPI 4: expert: A row = off+m, atomicAdd(C[list[off+m]*ldc+n], scale[off+m]*acc)
// EPI 5: atomicAdd(C[m*ldc+n], scale[m]*acc)
struct GemmP {
  const short* A; long long strideA; int adiv; int lda;
  const short* B; long long strideB; int bdiv; int ldb;
  void* C; long long strideC; int cdiv; int ldc;
  const int* e_off; const int* e_cnt;
  const int* list; const float* scale;
  float alpha;
  int M, N, K;
  int cskip, ckb;
  int ksplit, kchunk;
};

template<int EPI>
__global__ __launch_bounds__(256) void gemm_bt(GemmP p) {
  constexpr int BM = 128, BN = 128, BK = 32;
  __shared__ __align__(16) short As[2][BM * BK];
  __shared__ __align__(16) short Bs[2][BN * BK];
  const int zz = blockIdx.z;
  const int zo = zz / p.ksplit;
  const int kc = zz - zo * p.ksplit;
  const int m0 = blockIdx.y * BM;
  const int n0 = blockIdx.x * BN;
  int off = 0, cnt = p.M;
  if constexpr (EPI == 3 || EPI == 4) {
    off = p.e_off[zo]; cnt = p.e_cnt[zo];
    if (m0 >= cnt) return;
  }
  if (p.cskip && n0 >= m0 + BM) return;
  int kend = p.ckb ? min(m0 + BM, p.K) : p.K;
  const int kbeg = kc * p.kchunk;
  kend = min(kend, kbeg + p.kchunk);
  if (kbeg >= kend) return;

  const short* Ab = p.A + (long long)(zo / p.adiv) * p.strideA;
  const short* Bb = p.B + (long long)(zo / p.bdiv) * p.strideB;

  const int tid = threadIdx.x;
  const int lane = tid & 63, wid = tid >> 6;
  const int wr = wid >> 1, wc = wid & 1;
  const int kg = lane >> 4, li = lane & 15;

  const int srow = tid >> 2, scol = (tid & 3) * 8;
  const short* aSrc[2];
  const short* bSrc[2];
  #pragma unroll
  for (int c = 0; c < 2; c++) {
    int ra = srow + c * 64;
    int gr;
    if constexpr (EPI == 3)      { int rr = m0 + ra; if (rr >= cnt) rr = cnt - 1; gr = p.list[off + rr]; }
    else if constexpr (EPI == 4) { int rr = m0 + ra; if (rr >= cnt) rr = cnt - 1; gr = off + rr; }
    else                         gr = m0 + ra;
    aSrc[c] = Ab + (long long)gr * p.lda + scol;
    bSrc[c] = Bb + (long long)(n0 + ra) * p.ldb + scol;
  }

  f32x4 acc[4][4];
  #pragma unroll
  for (int i = 0; i < 4; i++)
    #pragma unroll
    for (int j = 0; j < 4; j++) acc[i][j] = (f32x4){0.f, 0.f, 0.f, 0.f};

  // prologue: stage first tile into buf 0
  #pragma unroll
  for (int c = 0; c < 2; c++) {
    gload16(aSrc[c] + kbeg, &As[0][tid * 8 + c * 2048]);
    gload16(bSrc[c] + kbeg, &Bs[0][tid * 8 + c * 2048]);
  }
  __syncthreads();

  int cur = 0;
  for (int k0 = kbeg; k0 < kend; k0 += BK) {
    // issue next-tile loads into the other buffer
    const int nk = k0 + BK;
    if (nk < kend) {
      #pragma unroll
      for (int c = 0; c < 2; c++) {
        gload16(aSrc[c] + nk, &As[cur ^ 1][tid * 8 + c * 2048]);
        gload16(bSrc[c] + nk, &Bs[cur ^ 1][tid * 8 + c * 2048]);
      }
    }
    bf16x8 av[4], bv[4];
    #pragma unroll
    for (int mi = 0; mi < 4; mi++)
      av[mi] = *(const bf16x8*)&As[cur][(wr * 64 + mi * 16 + li) * BK + kg * 8];
    #pragma unroll
    for (int nj = 0; nj < 4; nj++)
      bv[nj] = *(const bf16x8*)&Bs[cur][(wc * 64 + nj * 16 + li) * BK + kg * 8];
    #pragma unroll
    for (int mi = 0; mi < 4; mi++)
      #pragma unroll
      for (int nj = 0; nj < 4; nj++)
        acc[mi][nj] = mfma16(av[mi], bv[nj], acc[mi][nj]);
    __syncthreads();   // drains vmcnt (next tile landed) + orders LDS reuse
    cur ^= 1;
  }

  const long long zc = (long long)(zo / p.cdiv) * p.strideC;
  #pragma unroll
  for (int mi = 0; mi < 4; mi++) {
    #pragma unroll
    for (int nj = 0; nj < 4; nj++) {
      #pragma unroll
      for (int r = 0; r < 4; r++) {
        int ml = wr * 64 + mi * 16 + kg * 4 + r;
        int nl2 = wc * 64 + nj * 16 + li;
        int mg = m0 + ml, ng = n0 + nl2;
        float v = acc[mi][nj][r] * p.alpha;
        if constexpr (EPI == 0) {
          float* C = (float*)p.C + zc;
          C[(long long)mg * p.ldc + ng] = v;
        } else if constexpr (EPI == 1) {
          float* C = (float*)p.C + zc;
          atomicAdd(&C[(long long)mg * p.ldc + ng], v);
        } else if constexpr (EPI == 3) {
          if (mg < cnt) {
            float* C = (float*)p.C;
            atomicAdd(&C[(long long)(off + mg) * p.ldc + ng], v);
          }
        } else if constexpr (EPI == 4) {
          if (mg < cnt) {
            float* C = (float*)p.C;
            int tok = p.list[off + mg];
            atomicAdd(&C[(long long)tok * p.ldc + ng], p.scale[off + mg] * v);
          }
        } else if constexpr (EPI == 5) {
          float* C = (float*)p.C;
          atomicAdd(&C[(long long)mg * p.ldc + ng], p.scale[mg] * v);
        }
      }
    }
  }
}

// ---------- aux kernels ----------
__global__ __launch_bounds__(256) void rope_table_k(const int* pos_ids, float* ct, float* st) {
  int i = blockIdx.x * 256 + threadIdx.x;          // 1024*64
  int p = i >> 6, f = i & 63;
  float pos = (float)pos_ids[p];
  float inv = powf(1.0e6f, -(float)f * (1.f / 64.f));
  float a = pos * inv;
  ct[i] = cosf(a); st[i] = sinf(a);
}

__global__ __launch_bounds__(256) void rmsnorm_k(const float* x, const float* w, short* o,
                                                 float* copy_out, float* rs_out) {
  __shared__ float sbuf[4];
  int t = blockIdx.x;
  const float* xr = x + (long long)t * H_;
  float ss = 0.f;
  for (int i = threadIdx.x; i < H_ / 4; i += 256) {
    float4 v = ((const float4*)xr)[i];
    ss += v.x * v.x + v.y * v.y + v.z * v.z + v.w * v.w;
  }
  ss = block_reduce<false>(ss, sbuf);
  float rs = rsqrtf(ss * (1.f / (float)H_) + 1e-6f);
  for (int i = threadIdx.x; i < H_; i += 256) {
    float xv = xr[i];
    o[(long long)t * H_ + i] = f2bf(xv * rs * w[i]);
    if (copy_out) copy_out[(long long)t * H_ + i] = xv;
  }
  if (rs_out && threadIdx.x == 0) rs_out[t] = rs;
}

__global__ __launch_bounds__(256) void bias_init_k(const float* qb, const float* kb,
                                                   const float* vb, float* qkv) {
  int i = blockIdx.x * 256 + threadIdx.x;          // 1024*3072
  int j = i & 3071;
  float b = (j < 2048) ? qb[j] : ((j < 2560) ? kb[j - 2048] : vb[j - 2560]);
  qkv[i] = b;
}

// RoPE from fused qkv fp32 [t, 3072] slice -> bf16 [t, width]
__global__ __launch_bounds__(256) void rope_apply_k(const float* src, short* dst, const float* ct,
                                                    const float* st, int srcoff, int width, int total) {
  int i = blockIdx.x * 256 + threadIdx.x;
  if (i >= total) return;
  int t = i / width, j = i - t * width;
  int d = j & 127, f = d & 63;
  float c = ct[t * 64 + f], s = st[t * 64 + f];
  const float* row = src + (long long)t * 3072 + srcoff;
  float xv = row[j];
  float ov = (d < 64) ? -row[j + 64] : row[j - 64];
  dst[i] = f2bf(xv * c + ov * s);
}

__global__ __launch_bounds__(256) void vtrans_k(const float* qkv, short* vt) {
  int i = blockIdx.x * 256 + threadIdx.x;          // kvh*131072 + d*1024 + s
  int kvh = i >> 17, rem = i & 131071;
  int d = rem >> 10, s_ = rem & 1023;
  vt[i] = f2bf(qkv[(long long)s_ * 3072 + 2560 + kvh * 128 + d]);
}

__global__ __launch_bounds__(256) void cvt_bf16_k(const float* src, short* dst, int total) {
  int i = blockIdx.x * 256 + threadIdx.x;
  if (i < total) dst[i] = f2bf(src[i]);
}

__global__ __launch_bounds__(256) void softmax_k(const float* sc, short* P) {
  __shared__ float sbuf[4];
  long long row = blockIdx.x;                      // h*1024+q
  int q = (int)(row & (S_ - 1));
  const float* sr = sc + row * S_;
  short* pr = P + row * S_;
  int L = q + 1;
  float mx = -3.4e38f;
  for (int i = threadIdx.x; i < L; i += 256) mx = fmaxf(mx, sr[i]);
  mx = block_reduce<true>(mx, sbuf);
  float s = 0.f;
  for (int i = threadIdx.x; i < L; i += 256) s += __expf(sr[i] - mx);
  s = block_reduce<false>(s, sbuf);
  float inv = 1.f / s;
  for (int i = threadIdx.x; i < S_; i += 256) {
    float pv = (i < L) ? __expf(sr[i] - mx) * inv : 0.f;
    pr[i] = f2bf(pv);
  }
}

__global__ void router_k(const float* h2, const float* rs, const float* w2,
                         const float* rw, const float* sgw,
                         int* top_i, float* top_w, float* sg_sig, int* counts) {
  int t = blockIdx.x;
  int l = threadIdx.x;   // 64 threads
  float le[8] = {0, 0, 0, 0, 0, 0, 0, 0};
  float ls = 0.f;
  float r = rs[t];
  for (int k = l; k < H_; k += 64) {
    float xv = h2[(long long)t * H_ + k] * r * w2[k];
    ls += xv * sgw[k];
    const float* rk = rw + k * E_;
    #pragma unroll
    for (int e = 0; e < E_; e++) le[e] += xv * rk[e];
  }
  #pragma unroll
  for (int o = 32; o >= 1; o >>= 1) {
    ls += __shfl_down(ls, o);
    #pragma unroll
    for (int e = 0; e < E_; e++) le[e] += __shfl_down(le[e], o);
  }
  if (l == 0) {
    float m = le[0];
    for (int e = 1; e < E_; e++) m = fmaxf(m, le[e]);
    float pe[8], s = 0.f;
    for (int e = 0; e < E_; e++) { pe[e] = __expf(le[e] - m); s += pe[e]; }
    float inv = 1.f / s;
    for (int e = 0; e < E_; e++) pe[e] *= inv;
    int i1 = 0;
    for (int e = 1; e < E_; e++) if (pe[e] > pe[i1]) i1 = e;
    int i2 = -1;
    for (int e = 0; e < E_; e++) if (e != i1 && (i2 < 0 || pe[e] > pe[i2])) i2 = e;
    top_i[2 * t] = i1; top_i[2 * t + 1] = i2;
    top_w[2 * t] = pe[i1]; top_w[2 * t + 1] = pe[i2];
    sg_sig[t] = 1.f / (1.f + __expf(-ls));
    atomicAdd(&counts[i1], 1); atomicAdd(&counts[i2], 1);
  }
}

__global__ void scan_k(const int* counts, int* offs) {
  if (threadIdx.x == 0 && blockIdx.x == 0) {
    int s = 0;
    for (int e = 0; e < E_; e++) { offs[e] = s; s += counts[e]; }
  }
}

__global__ __launch_bounds__(256) void fill_k(const int* top_i, const float* top_w, const int* offs,
                                              int* pos, int* list, float* pw) {
  int t = blockIdx.x * 256 + threadIdx.x;
  if (t >= S_) return;
  for (int j = 0; j < 2; j++) {
    int e = top_i[2 * t + j];
    int p_ = atomicAdd(&pos[e], 1);
    int slot = offs[e] + p_;
    list[slot] = t; pw[slot] = top_w[2 * t + j];
  }
}

// fused silu: src fp32 rows of [srcld], g at col j, u at col half+j -> dst bf16 [t*half+j]
__global__ __launch_bounds__(256) void silu_mul_k(const float* src, short* dst, int half,
                                                  int srcld, int total) {
  int i = blockIdx.x * 256 + threadIdx.x;
  if (i >= total) return;
  int t = i / half, j = i - t * half;
  const float* row = src + (long long)t * srcld;
  float g = row[j], u = row[half + j];
  float sig = 1.f / (1.f + __expf(-g));
  dst[i] = f2bf(g * sig * u);
}

// ---------- host ----------
static GemmP mkp() {
  GemmP p{};
  p.adiv = 1; p.bdiv = 1; p.cdiv = 1; p.alpha = 1.f;
  p.ksplit = 1; p.kchunk = 1 << 30;
  return p;
}

extern "C" void kernel_launch(void* const* d_in, const int* in_sizes, int n_in,
                              void* d_out, int out_size, void* d_ws, size_t ws_size,
                              hipStream_t stream) {
  const float* hidden   = (const float*)d_in[0];
  const int*   pos_ids  = (const int*)d_in[1];
  const float* ln1_w    = (const float*)d_in[2];
  const float* ln2_w    = (const float*)d_in[3];
  const float* q_w      = (const float*)d_in[4];
  const float* q_b      = (const float*)d_in[5];
  const float* k_w      = (const float*)d_in[6];
  const float* k_b      = (const float*)d_in[7];
  const float* v_w      = (const float*)d_in[8];
  const float* v_b      = (const float*)d_in[9];
  const float* o_w      = (const float*)d_in[10];
  const float* router_w = (const float*)d_in[11];
  const float* e_gate   = (const float*)d_in[12];
  const float* e_up     = (const float*)d_in[13];
  const float* e_down   = (const float*)d_in[14];
  const float* s_gate   = (const float*)d_in[15];
  const float* s_up     = (const float*)d_in[16];
  const float* s_down   = (const float*)d_in[17];
  const float* sg_w     = (const float*)d_in[18];
  float* out = (float*)d_out;

  char* base = (char*)d_ws;
  size_t off_ = 0;
  auto alc = [&](size_t nbytes) -> char* {
    off_ = (off_ + 255) & ~(size_t)255;
    char* p = base + off_;
    off_ += nbytes;
    return p;
  };
  // transposed bf16 weights
  short* qkvT = (short*)alc((size_t)3072 * H_ * 2);          // rows: q 0..2047, k 2048..2559, v 2560..3071
  short* oT   = (short*)alc((size_t)H_ * H_ * 2);
  short* eguT = (short*)alc((size_t)E_ * 2816 * H_ * 2);     // per expert: gate rows 0..1407, up 1408..2815
  short* edT  = (short*)alc((size_t)E_ * H_ * IM_ * 2);
  short* sguT = (short*)alc((size_t)11264 * H_ * 2);         // gate rows 0..5631, up 5632..11263
  short* sdT  = (short*)alc((size_t)H_ * ISH_ * 2);
  // activations
  short* x1      = (short*)alc((size_t)S_ * H_ * 2);
  float* qkv_f   = (float*)alc((size_t)S_ * 3072 * 4);
  float* ct      = (float*)alc((size_t)S_ * 64 * 4);
  float* st      = (float*)alc((size_t)S_ * 64 * 4);
  short* qr      = (short*)alc((size_t)S_ * H_ * 2);
  short* kr      = (short*)alc((size_t)S_ * 512 * 2);
  short* vt      = (short*)alc((size_t)S_ * 512 * 2);
  float* attn_f  = (float*)alc((size_t)S_ * H_ * 4);
  short* attn    = (short*)alc((size_t)S_ * H_ * 2);
  float* h2      = (float*)alc((size_t)S_ * H_ * 4);
  short* x2      = (short*)alc((size_t)S_ * H_ * 2);
  float* rs2     = (float*)alc(S_ * 4);
  int*   top_i   = (int*)alc(2 * S_ * 4);
  float* top_w   = (float*)alc(2 * S_ * 4);
  float* sg_sig  = (float*)alc(S_ * 4);
  int*   counts  = (int*)alc(64);
  int*   pos     = counts + 8;
  int*   offs    = (int*)alc(32);
  int*   list    = (int*)alc(2 * S_ * 4);
  float* pw      = (float*)alc(2 * S_ * 4);
  char*  region  = alc(100663296);   // 96 MiB overlay
  float* scores  = (float*)region;                            // 64 MiB
  short* P       = (short*)(region + 67108864);               // 32 MiB
  float* g_moeF  = (float*)region;                            // 2048x2816 fp32 = 23 MB
  short* gu_moeB = (short*)(region + 23068672);               // 2048x1408 bf16
  float* gushF   = (float*)(region + 28835840);               // 1024x11264 fp32 = 46 MB
  short* gushB   = (short*)(region + 74973184);               // 1024x5632 bf16

  // 0) weight transpose+convert
  transpose_k<<<dim3(32, 32, 1), 256, 0, stream>>>(q_w, qkvT, H_, H_, 0, 0);
  transpose_k<<<dim3(8, 32, 1), 256, 0, stream>>>(k_w, qkvT + (size_t)2048 * H_, H_, 512, 0, 0);
  transpose_k<<<dim3(8, 32, 1), 256, 0, stream>>>(v_w, qkvT + (size_t)2560 * H_, H_, 512, 0, 0);
  transpose_k<<<dim3(32, 32, 1), 256, 0, stream>>>(o_w, oT, H_, H_, 0, 0);
  transpose_k<<<dim3(22, 32, E_), 256, 0, stream>>>(e_gate, eguT, H_, IM_,
                                                    (long long)H_ * IM_, (long long)2816 * H_);
  transpose_k<<<dim3(22, 32, E_), 256, 0, stream>>>(e_up, eguT + (size_t)1408 * H_, H_, IM_,
                                                    (long long)H_ * IM_, (long long)2816 * H_);
  transpose_k<<<dim3(32, 22, E_), 256, 0, stream>>>(e_down, edT, IM_, H_,
                                                    (long long)IM_ * H_, (long long)IM_ * H_);
  transpose_k<<<dim3(88, 32, 1), 256, 0, stream>>>(s_gate, sguT, H_, ISH_, 0, 0);
  transpose_k<<<dim3(88, 32, 1), 256, 0, stream>>>(s_up, sguT + (size_t)5632 * H_, H_, ISH_, 0, 0);
  transpose_k<<<dim3(32, 88, 1), 256, 0, stream>>>(s_down, sdT, ISH_, H_, 0, 0);

  // 1) rope tables + rmsnorm1; h2 pre-init with residual
  rope_table_k<<<256, 256, 0, stream>>>(pos_ids, ct, st);
  rmsnorm_k<<<S_, 256, 0, stream>>>(hidden, ln1_w, x1, nullptr, nullptr);
  hipMemcpyAsync(h2, hidden, (size_t)S_ * H_ * 4, hipMemcpyDeviceToDevice, stream);
  hipMemsetAsync(attn_f, 0, (size_t)S_ * H_ * 4, stream);

  // 2) fused QKV projection (split-K=2, atomic into bias-initialized buffer)
  bias_init_k<<<12288, 256, 0, stream>>>(q_b, k_b, v_b, qkv_f);
  {
    GemmP p = mkp();
    p.A = x1; p.lda = H_;
    p.B = qkvT; p.ldb = H_;
    p.C = qkv_f; p.ldc = 3072;
    p.M = S_; p.N = 3072; p.K = H_;
    p.ksplit = 2; p.kchunk = 1024;
    gemm_bt<1><<<dim3(24, 8, 2), 256, 0, stream>>>(p);
  }

  // 3) RoPE + V transpose
  rope_apply_k<<<8192, 256, 0, stream>>>(qkv_f, qr, ct, st, 0, 2048, S_ * H_);
  rope_apply_k<<<2048, 256, 0, stream>>>(qkv_f, kr, ct, st, 2048, 512, S_ * 512);
  vtrans_k<<<2048, 256, 0, stream>>>(qkv_f, vt);

  // 4) scores = scale * Q K^T (causal tiles only)
  {
    GemmP p = mkp();
    p.A = qr; p.strideA = HD_; p.lda = H_;
    p.B = kr; p.strideB = HD_; p.bdiv = 4; p.ldb = 512;
    p.C = scores; p.strideC = (long long)S_ * S_; p.ldc = S_;
    p.alpha = 0.08838834764831845f;
    p.M = S_; p.N = S_; p.K = HD_; p.cskip = 1;
    p.kchunk = HD_;
    gemm_bt<0><<<dim3(8, 8, NH_), 256, 0, stream>>>(p);
  }
  softmax_k<<<NH_ * S_, 256, 0, stream>>>(scores, P);
  // 5) attn = P @ V  (split-K=4 over causal K, atomic into zeroed fp32)
  {
    GemmP p = mkp();
    p.A = P; p.strideA = (long long)S_ * S_; p.lda = S_;
    p.B = vt; p.strideB = (long long)HD_ * S_; p.bdiv = 4; p.ldb = S_;
    p.C = attn_f; p.strideC = HD_; p.ldc = H_;
    p.M = S_; p.N = HD_; p.K = S_; p.ckb = 1;
    p.ksplit = 4; p.kchunk = 256;
    gemm_bt<1><<<dim3(1, 8, NH_ * 4), 256, 0, stream>>>(p);
  }
  cvt_bf16_k<<<8192, 256, 0, stream>>>(attn_f, attn, S_ * H_);
  // 6) O-proj + residual -> h2 (pre-initialized with hidden), split-K=4
  {
    GemmP p = mkp();
    p.A = attn; p.lda = H_;
    p.B = oT; p.ldb = H_;
    p.C = h2; p.ldc = H_;
    p.M = S_; p.N = H_; p.K = H_;
    p.ksplit = 4; p.kchunk = 512;
    gemm_bt<1><<<dim3(16, 8, 4), 256, 0, stream>>>(p);
  }

  // 7) rmsnorm2 (x2 bf16; copy h2 -> d_out as accumulator base; save 1/rms)
  rmsnorm_k<<<S_, 256, 0, stream>>>(h2, ln2_w, x2, out, rs2);

  // 8) router / top-2 / gather lists
  hipMemsetAsync(counts, 0, 64, stream);
  router_k<<<S_, 64, 0, stream>>>(h2, rs2, ln2_w, router_w, sg_w, top_i, top_w, sg_sig, counts);
  scan_k<<<1, 1, 0, stream>>>(counts, offs);
  fill_k<<<4, 256, 0, stream>>>(top_i, top_w, offs, pos, list, pw);

  // 9) experts: fused gate+up (gathered, split-K=2), silu, down (scatter, split-K=2)
  hipMemsetAsync(g_moeF, 0, (size_t)2048 * 2816 * 4, stream);
  {
    GemmP p = mkp();
    p.A = x2; p.lda = H_;
    p.B = eguT; p.strideB = (long long)2816 * H_; p.ldb = H_;
    p.C = g_moeF; p.ldc = 2816;
    p.e_off = offs; p.e_cnt = counts; p.list = list;
    p.M = S_; p.N = 2816; p.K = H_;
    p.ksplit = 2; p.kchunk = 1024;
    gemm_bt<3><<<dim3(22, 8, E_ * 2), 256, 0, stream>>>(p);
  }
  silu_mul_k<<<11264, 256, 0, stream>>>(g_moeF, gu_moeB, IM_, 2816, 2048 * IM_);
  {
    GemmP p = mkp();
    p.A = gu_moeB; p.lda = IM_;
    p.B = edT; p.strideB = (long long)H_ * IM_; p.ldb = IM_;
    p.C = out; p.ldc = H_;
    p.e_off = offs; p.e_cnt = counts; p.list = list; p.scale = pw;
    p.M = S_; p.N = H_; p.K = IM_;
    p.ksplit = 2; p.kchunk = 704;
    gemm_bt<4><<<dim3(16, 8, E_ * 2), 256, 0, stream>>>(p);
  }

  // 10) shared expert: fused gate+up (704 blocks, plain store), silu, down (split-K=4)
  {
    GemmP p = mkp();
    p.A = x2; p.lda = H_;
    p.B = sguT; p.ldb = H_;
    p.C = gushF; p.ldc = 11264;
    p.M = S_; p.N = 11264; p.K = H_;
    p.kchunk = H_;
    gemm_bt<0><<<dim3(88, 8, 1), 256, 0, stream>>>(p);
  }
  silu_mul_k<<<22528, 256, 0, stream>>>(gushF, gushB, ISH_, 11264, S_ * ISH_);
  {
    GemmP p = mkp();
    p.A = gushB; p.lda = ISH_;
    p.B = sdT; p.ldb = ISH_;
    p.C = out; p.ldc = H_; p.scale = sg_sig;
    p.M = S_; p.N = H_; p.K = ISH_;
    p.ksplit = 4; p.kchunk = 1408;
    gemm_bt<5><<<dim3(16, 8, 4), 256, 0, stream>>>(p);
  }
}